// Round 11
// baseline (5345.132 us; speedup 1.0000x reference)
//
#include <hip/hip_runtime.h>

typedef unsigned short u16;
typedef unsigned int u32;
typedef short bf16x8 __attribute__((ext_vector_type(8)));
typedef short bf16x4 __attribute__((ext_vector_type(4)));
typedef float f32x4 __attribute__((ext_vector_type(4)));

#define LOG2E 1.4426950408889634f

__device__ __forceinline__ u16 f2b(float f) {
  u32 u = __builtin_bit_cast(u32, f);
  u32 r = (u + 0x7FFFu + ((u >> 16) & 1u)) >> 16;
  return (u16)r;
}
__device__ __forceinline__ float b2f(u16 h) {
  u32 u = ((u32)h) << 16;
  return __builtin_bit_cast(float, u);
}

// 8 consecutive elements as bf16x8; F32 selects fp32-source (convert) vs bf16.
template <bool F32>
__device__ __forceinline__ bf16x8 load8(const void* base, size_t idx) {
  if (F32) {
    const float* p = (const float*)base + idx;
    const f32x4 a = *(const f32x4*)p;
    const f32x4 b = *(const f32x4*)(p + 4);
    bf16x8 r = { (short)f2b(a[0]), (short)f2b(a[1]), (short)f2b(a[2]),
                 (short)f2b(a[3]), (short)f2b(b[0]), (short)f2b(b[1]),
                 (short)f2b(b[2]), (short)f2b(b[3]) };
    return r;
  }
  return *(const bf16x8*)((const u16*)base + idx);
}

// ---------------------------------------------------------------------------
// NT GEMM core (R9-verified): C[128x128] += A * W^T, K=1024.
// ---------------------------------------------------------------------------
template <bool AF32>
__device__ __forceinline__ void gemm_core(const void* A, const float* W,
                                          int m0, int n0, int tid,
                                          u16* As, u16* Bs,
                                          f32x4 (&acc)[4][4]) {
  const int lane = tid & 63, wave = tid >> 6;
  const int wr = wave >> 1, wc = wave & 1;
  const int l15 = lane & 15, quad = lane >> 4;
  const int r0 = tid >> 2;
  const int c8 = (tid & 3) << 3;

  const size_t ia0 = (size_t)(m0 + r0) * 1024 + c8;
  const size_t ia1 = ia0 + (size_t)64 * 1024;
  const size_t iw0 = (size_t)(n0 + r0) * 1024 + c8;
  const size_t iw1 = iw0 + (size_t)64 * 1024;

  u16* sa0 = As + r0 * 40 + c8;
  u16* sa1 = sa0 + 64 * 40;
  u16* sb0 = Bs + r0 * 40 + c8;
  u16* sb1 = sb0 + 64 * 40;

  const u16* ar = As + (wr * 64 + l15) * 40 + quad * 8;
  const u16* br = Bs + (wc * 64 + l15) * 40 + quad * 8;

  bf16x8 ra0 = load8<AF32>(A, ia0);
  bf16x8 ra1 = load8<AF32>(A, ia1);
  bf16x8 rw0 = load8<true>(W, iw0);
  bf16x8 rw1 = load8<true>(W, iw1);

  for (int k0 = 0; k0 < 1024; k0 += 32) {
    *(bf16x8*)sa0 = ra0;
    *(bf16x8*)sa1 = ra1;
    *(bf16x8*)sb0 = rw0;
    *(bf16x8*)sb1 = rw1;
    __syncthreads();
    if (k0 + 32 < 1024) {
      ra0 = load8<AF32>(A, ia0 + k0 + 32);
      ra1 = load8<AF32>(A, ia1 + k0 + 32);
      rw0 = load8<true>(W, iw0 + k0 + 32);
      rw1 = load8<true>(W, iw1 + k0 + 32);
    }
    bf16x8 af[4], bfr[4];
#pragma unroll
    for (int i = 0; i < 4; ++i) af[i] = *(const bf16x8*)(ar + i * 16 * 40);
#pragma unroll
    for (int i = 0; i < 4; ++i) bfr[i] = *(const bf16x8*)(br + i * 16 * 40);
#pragma unroll
    for (int mt = 0; mt < 4; ++mt)
#pragma unroll
      for (int nt = 0; nt < 4; ++nt)
        acc[mt][nt] = __builtin_amdgcn_mfma_f32_16x16x32_bf16(
            af[mt], bfr[nt], acc[mt][nt], 0, 0, 0);
    __syncthreads();
  }
}

// ---------------------------------------------------------------------------
// Fused QKV projection. x, W fp32 in; q/k bf16 token-major; V transposed:
// vt[(b*1024+e)*2048 + s]. blockIdx.y: [0..7]=Q, [8..15]=K, [16..23]=V.
// ---------------------------------------------------------------------------
__global__ __launch_bounds__(256, 2) void gemm_qkv_kernel(
    const float* __restrict__ x, const float* __restrict__ wq,
    const float* __restrict__ wk, const float* __restrict__ wv,
    u16* __restrict__ qo, u16* __restrict__ ko, u16* __restrict__ vt) {
  __shared__ __align__(16) u16 As[128 * 40];
  __shared__ __align__(16) u16 Bs[128 * 40];
  const int tid = threadIdx.x;
  const int m0 = blockIdx.x * 128;
  const int mat = blockIdx.y >> 3;
  const int n0 = (blockIdx.y & 7) * 128;
  const float* W = (mat == 0) ? wq : ((mat == 1) ? wk : wv);

  f32x4 acc[4][4] = {};
  gemm_core<true>(x, W, m0, n0, tid, As, Bs, acc);

  const int lane = tid & 63, wave = tid >> 6;
  const int wr = wave >> 1, wc = wave & 1;
  const int l15 = lane & 15, quad = lane >> 4;

  if (mat < 2) {
    u16* out = (mat == 0) ? qo : ko;
#pragma unroll
    for (int mt = 0; mt < 4; ++mt) {
      const int gr = m0 + wr * 64 + mt * 16 + quad * 4;
#pragma unroll
      for (int nt = 0; nt < 4; ++nt) {
        const int gc = n0 + wc * 64 + nt * 16 + l15;
#pragma unroll
        for (int r = 0; r < 4; ++r)
          out[(size_t)(gr + r) * 1024 + gc] = f2b(acc[mt][nt][r]);
      }
    }
  } else {
    // vt[(b*1024 + e)*2048 + s]; 4 consecutive s per lane -> 8B store
#pragma unroll
    for (int mt = 0; mt < 4; ++mt) {
      const int gr = m0 + wr * 64 + mt * 16 + quad * 4;  // token idx b*2048+s
      const int b = gr >> 11;
      const int s = gr & 2047;
#pragma unroll
      for (int nt = 0; nt < 4; ++nt) {
        const int gc = n0 + wc * 64 + nt * 16 + l15;     // embed dim e
        bf16x4 pk = { (short)f2b(acc[mt][nt][0]), (short)f2b(acc[mt][nt][1]),
                      (short)f2b(acc[mt][nt][2]), (short)f2b(acc[mt][nt][3]) };
        *(bf16x4*)&vt[(size_t)(b * 1024 + gc) * 2048 + s] = pk;
      }
    }
  }
}

// ---------------------------------------------------------------------------
// Output projection: out = ctx * Wo^T + bo. ctx bf16 (ws), Wo/bo fp32,
// out fp32 (verified R9).
// ---------------------------------------------------------------------------
__global__ __launch_bounds__(256, 2) void gemm_out_kernel(
    const u16* __restrict__ ctx, const float* __restrict__ wo,
    const float* __restrict__ bo, float* __restrict__ out) {
  __shared__ __align__(16) u16 As[128 * 40];
  __shared__ __align__(16) u16 Bs[128 * 40];
  const int tid = threadIdx.x;
  const int m0 = blockIdx.x * 128;
  const int n0 = blockIdx.y * 128;

  f32x4 acc[4][4] = {};
  gemm_core<false>(ctx, wo, m0, n0, tid, As, Bs, acc);

  const int lane = tid & 63, wave = tid >> 6;
  const int wr = wave >> 1, wc = wave & 1;
  const int l15 = lane & 15, quad = lane >> 4;
#pragma unroll
  for (int nt = 0; nt < 4; ++nt) {
    const int gc = n0 + wc * 64 + nt * 16 + l15;
    const float bv = bo[gc];
#pragma unroll
    for (int mt = 0; mt < 4; ++mt) {
      const int gr = m0 + wr * 64 + mt * 16 + quad * 4;
#pragma unroll
      for (int r = 0; r < 4; ++r)
        out[(size_t)(gr + r) * 1024 + gc] = acc[mt][nt][r] + bv;
    }
  }
}

// ---------------------------------------------------------------------------
// Wave-level MFMA flash, v2. Changes vs R10 (correctness-neutral):
//  - P-transform LDS tile stride 32 -> 36 u16 (l15*18 mod 32 = 16 distinct
//    banks -> kills the 8-way conflicts; 8.0e6 SQ_LDS_BANK_CONFLICT seen).
//  - Register double-buffered K-fragment prefetch (loop-carried loads).
//  - Blocks of 2 waves, grid (64,32), heavy-first mapping q0=(63-bx)*32
//    (LPT schedule: heavy causal tiles dispatch first, light fill tail).
// ctx aliases q: each wave reads only its own (b,rows,h) q-slice at start,
// writes the identical slice at the end; all slices disjoint across waves.
// ---------------------------------------------------------------------------
__global__ __launch_bounds__(128, 4) void flash_kernel(
    const u16* q, const u16* __restrict__ k,
    const u16* __restrict__ vt, u16* ctx) {
  __shared__ __align__(16) u16 plds_all[2][16 * 36];
  const int tid = threadIdx.x;
  const int wave = tid >> 6, lane = tid & 63;
  const int l15 = lane & 15, quad = lane >> 4;
  const int q0 = (63 - (int)blockIdx.x) * 32 + wave * 16;  // heavy-first
  const int bh = blockIdx.y;
  const int b = bh >> 4, h = bh & 15;
  const int m = q0 + l15;  // q-row this lane owns (as C-layout column)

  const u16* qrow = q + ((size_t)(b * 2048 + m) * 1024 + h * 64);
  const bf16x8 qf0 = *(const bf16x8*)(qrow + quad * 8);
  const bf16x8 qf1 = *(const bf16x8*)(qrow + 32 + quad * 8);
  const u16* kbase = k + (size_t)(b * 2048) * 1024 + h * 64;
  const u16* vbase = vt + (size_t)(b * 1024 + h * 64) * 2048;
  u16* plds = plds_all[wave];

  f32x4 o[4] = {};
  float m_run = -INFINITY, l_run = 0.0f;

  const int ntiles = (q0 + 47) >> 5;  // kv tiles of 32 covering kv <= q0+15

  // K fragment double buffer (prefetch pipeline)
  bf16x8 kf[2][4];
  {
    const u16* kr0 = kbase + (size_t)l15 * 1024 + quad * 8;
    const u16* kr1 = kbase + (size_t)(16 + l15) * 1024 + quad * 8;
    kf[0][0] = *(const bf16x8*)(kr0);
    kf[0][1] = *(const bf16x8*)(kr0 + 32);
    kf[0][2] = *(const bf16x8*)(kr1);
    kf[0][3] = *(const bf16x8*)(kr1 + 32);
  }

  for (int t = 0; t < ntiles; ++t) {
    const int n0 = t * 32;
    const int cur = t & 1;
    if (t + 1 < ntiles) {  // prefetch next K tile while this one computes
      const int nn = n0 + 32;
      const u16* kr0 = kbase + (size_t)(nn + l15) * 1024 + quad * 8;
      const u16* kr1 = kbase + (size_t)(nn + 16 + l15) * 1024 + quad * 8;
      kf[cur ^ 1][0] = *(const bf16x8*)(kr0);
      kf[cur ^ 1][1] = *(const bf16x8*)(kr0 + 32);
      kf[cur ^ 1][2] = *(const bf16x8*)(kr1);
      kf[cur ^ 1][3] = *(const bf16x8*)(kr1 + 32);
    }
    // V loads are dependence-free; issue early.
    bf16x8 vf[4];
#pragma unroll
    for (int dt = 0; dt < 4; ++dt)
      vf[dt] = *(const bf16x8*)(vbase + (size_t)(dt * 16 + l15) * 2048 + n0 + quad * 8);

    f32x4 st0 = {}, st1 = {};
    st0 = __builtin_amdgcn_mfma_f32_16x16x32_bf16(kf[cur][0], qf0, st0, 0, 0, 0);
    st0 = __builtin_amdgcn_mfma_f32_16x16x32_bf16(kf[cur][1], qf1, st0, 0, 0, 0);
    st1 = __builtin_amdgcn_mfma_f32_16x16x32_bf16(kf[cur][2], qf0, st1, 0, 0, 0);
    st1 = __builtin_amdgcn_mfma_f32_16x16x32_bf16(kf[cur][3], qf1, st1, 0, 0, 0);

    float s[8];
#pragma unroll
    for (int r = 0; r < 4; ++r) {
      s[r] = st0[r] * 0.125f;
      s[4 + r] = st1[r] * 0.125f;
    }
    const int nb = n0 + quad * 4;  // st0 reg r -> kv=nb+r; st1 -> kv=nb+16+r
#pragma unroll
    for (int r = 0; r < 4; ++r) {
      if (nb + r > m) s[r] = -INFINITY;
      if (nb + 16 + r > m) s[4 + r] = -INFINITY;
    }
    float mx = s[0];
#pragma unroll
    for (int i = 1; i < 8; ++i) mx = fmaxf(mx, s[i]);
    mx = fmaxf(mx, __shfl_xor(mx, 16));
    mx = fmaxf(mx, __shfl_xor(mx, 32));
    const float m_new = fmaxf(m_run, mx);
    const float alpha = exp2f((m_run - m_new) * LOG2E);  // 0 on first tile

    float p[8];
    float sum = 0.0f;
#pragma unroll
    for (int i = 0; i < 8; ++i) {
      p[i] = exp2f((s[i] - m_new) * LOG2E);
      sum += p[i];
    }
    sum += __shfl_xor(sum, 16);
    sum += __shfl_xor(sum, 32);
    l_run = l_run * alpha + sum;
    m_run = m_new;
#pragma unroll
    for (int dt = 0; dt < 4; ++dt) o[dt] *= alpha;

    // P (C-layout) -> LDS [q][kv'] (stride 36) -> A/B-layout fragment
    bf16x4 pk0 = { (short)f2b(p[0]), (short)f2b(p[1]),
                   (short)f2b(p[2]), (short)f2b(p[3]) };
    bf16x4 pk1 = { (short)f2b(p[4]), (short)f2b(p[5]),
                   (short)f2b(p[6]), (short)f2b(p[7]) };
    *(bf16x4*)&plds[l15 * 36 + quad * 4] = pk0;
    *(bf16x4*)&plds[l15 * 36 + 16 + quad * 4] = pk1;
    asm volatile("s_waitcnt lgkmcnt(0)" ::: "memory");
    const bf16x8 pf = *(const bf16x8*)&plds[l15 * 36 + quad * 8];

#pragma unroll
    for (int dt = 0; dt < 4; ++dt)
      o[dt] = __builtin_amdgcn_mfma_f32_16x16x32_bf16(vf[dt], pf, o[dt], 0, 0, 0);
  }

  const float inv = 1.0f / l_run;
  u16* crow = ctx + ((size_t)(b * 2048 + q0 + l15) * 1024 + h * 64);
#pragma unroll
  for (int dt = 0; dt < 4; ++dt) {
    bf16x4 ov = { (short)f2b(o[dt][0] * inv), (short)f2b(o[dt][1] * inv),
                  (short)f2b(o[dt][2] * inv), (short)f2b(o[dt][3] * inv) };
    *(bf16x4*)&crow[dt * 16 + quad * 4] = ov;
  }
}

// ---------------------------------------------------------------------------
extern "C" void kernel_launch(void* const* d_in, const int* in_sizes, int n_in,
                              void* d_out, int out_size, void* d_ws,
                              size_t ws_size, hipStream_t stream) {
  // Interface (R9-verified): inputs fp32 in dict order, output fp32.
  const float* x  = (const float*)d_in[0];
  const float* wq = (const float*)d_in[1];
  const float* wk = (const float*)d_in[2];
  const float* wv = (const float*)d_in[3];
  const float* wo = (const float*)d_in[4];
  const float* bo = (const float*)d_in[5];
  float* out = (float*)d_out;

  // ws (bf16 elems): qb [0,4M) (aliased as ctx), kb [4M,8M),
  // vt [8M,12M) transposed V. 24 MiB.
  u16* qb = (u16*)d_ws;
  u16* kb = qb + 4194304u;
  u16* vt = kb + 4194304u;
  u16* ctx = qb;

  gemm_qkv_kernel<<<dim3(32, 24), 256, 0, stream>>>(x, wq, wk, wv, qb, kb, vt);
  flash_kernel<<<dim3(64, 32), 128, 0, stream>>>(qb, kb, vt, ctx);
  gemm_out_kernel<<<dim3(32, 8), 256, 0, stream>>>(ctx, wo, bo, out);
}

// Round 12
// 384.874 us; speedup vs baseline: 13.8880x; 13.8880x over previous
//
#include <hip/hip_runtime.h>

typedef unsigned short u16;
typedef unsigned int u32;
typedef short bf16x8 __attribute__((ext_vector_type(8)));
typedef short bf16x4 __attribute__((ext_vector_type(4)));
typedef float f32x4 __attribute__((ext_vector_type(4)));

#define LOG2E 1.4426950408889634f

__device__ __forceinline__ u16 f2b(float f) {
  u32 u = __builtin_bit_cast(u32, f);
  u32 r = (u + 0x7FFFu + ((u >> 16) & 1u)) >> 16;
  return (u16)r;
}
__device__ __forceinline__ float b2f(u16 h) {
  u32 u = ((u32)h) << 16;
  return __builtin_bit_cast(float, u);
}

// 8 consecutive elements as bf16x8; F32 selects fp32-source (convert) vs bf16.
template <bool F32>
__device__ __forceinline__ bf16x8 load8(const void* base, size_t idx) {
  if (F32) {
    const float* p = (const float*)base + idx;
    const f32x4 a = *(const f32x4*)p;
    const f32x4 b = *(const f32x4*)(p + 4);
    bf16x8 r = { (short)f2b(a[0]), (short)f2b(a[1]), (short)f2b(a[2]),
                 (short)f2b(a[3]), (short)f2b(b[0]), (short)f2b(b[1]),
                 (short)f2b(b[2]), (short)f2b(b[3]) };
    return r;
  }
  return *(const bf16x8*)((const u16*)base + idx);
}

// ---------------------------------------------------------------------------
// NT GEMM core (R9-verified): C[128x128] += A * W^T, K=1024.
// ---------------------------------------------------------------------------
template <bool AF32>
__device__ __forceinline__ void gemm_core(const void* A, const float* W,
                                          int m0, int n0, int tid,
                                          u16* As, u16* Bs,
                                          f32x4 (&acc)[4][4]) {
  const int lane = tid & 63, wave = tid >> 6;
  const int wr = wave >> 1, wc = wave & 1;
  const int l15 = lane & 15, quad = lane >> 4;
  const int r0 = tid >> 2;
  const int c8 = (tid & 3) << 3;

  const size_t ia0 = (size_t)(m0 + r0) * 1024 + c8;
  const size_t ia1 = ia0 + (size_t)64 * 1024;
  const size_t iw0 = (size_t)(n0 + r0) * 1024 + c8;
  const size_t iw1 = iw0 + (size_t)64 * 1024;

  u16* sa0 = As + r0 * 40 + c8;
  u16* sa1 = sa0 + 64 * 40;
  u16* sb0 = Bs + r0 * 40 + c8;
  u16* sb1 = sb0 + 64 * 40;

  const u16* ar = As + (wr * 64 + l15) * 40 + quad * 8;
  const u16* br = Bs + (wc * 64 + l15) * 40 + quad * 8;

  bf16x8 ra0 = load8<AF32>(A, ia0);
  bf16x8 ra1 = load8<AF32>(A, ia1);
  bf16x8 rw0 = load8<true>(W, iw0);
  bf16x8 rw1 = load8<true>(W, iw1);

  for (int k0 = 0; k0 < 1024; k0 += 32) {
    *(bf16x8*)sa0 = ra0;
    *(bf16x8*)sa1 = ra1;
    *(bf16x8*)sb0 = rw0;
    *(bf16x8*)sb1 = rw1;
    __syncthreads();
    if (k0 + 32 < 1024) {
      ra0 = load8<AF32>(A, ia0 + k0 + 32);
      ra1 = load8<AF32>(A, ia1 + k0 + 32);
      rw0 = load8<true>(W, iw0 + k0 + 32);
      rw1 = load8<true>(W, iw1 + k0 + 32);
    }
    bf16x8 af[4], bfr[4];
#pragma unroll
    for (int i = 0; i < 4; ++i) af[i] = *(const bf16x8*)(ar + i * 16 * 40);
#pragma unroll
    for (int i = 0; i < 4; ++i) bfr[i] = *(const bf16x8*)(br + i * 16 * 40);
#pragma unroll
    for (int mt = 0; mt < 4; ++mt)
#pragma unroll
      for (int nt = 0; nt < 4; ++nt)
        acc[mt][nt] = __builtin_amdgcn_mfma_f32_16x16x32_bf16(
            af[mt], bfr[nt], acc[mt][nt], 0, 0, 0);
    __syncthreads();
  }
}

// ---------------------------------------------------------------------------
// Fused QKV projection. x, W fp32 in; q/k bf16 token-major; V transposed:
// vt[(b*1024+e)*2048 + s]. blockIdx.y: [0..7]=Q, [8..15]=K, [16..23]=V.
// ---------------------------------------------------------------------------
__global__ __launch_bounds__(256, 2) void gemm_qkv_kernel(
    const float* __restrict__ x, const float* __restrict__ wq,
    const float* __restrict__ wk, const float* __restrict__ wv,
    u16* __restrict__ qo, u16* __restrict__ ko, u16* __restrict__ vt) {
  __shared__ __align__(16) u16 As[128 * 40];
  __shared__ __align__(16) u16 Bs[128 * 40];
  const int tid = threadIdx.x;
  const int m0 = blockIdx.x * 128;
  const int mat = blockIdx.y >> 3;
  const int n0 = (blockIdx.y & 7) * 128;
  const float* W = (mat == 0) ? wq : ((mat == 1) ? wk : wv);

  f32x4 acc[4][4] = {};
  gemm_core<true>(x, W, m0, n0, tid, As, Bs, acc);

  const int lane = tid & 63, wave = tid >> 6;
  const int wr = wave >> 1, wc = wave & 1;
  const int l15 = lane & 15, quad = lane >> 4;

  if (mat < 2) {
    u16* out = (mat == 0) ? qo : ko;
#pragma unroll
    for (int mt = 0; mt < 4; ++mt) {
      const int gr = m0 + wr * 64 + mt * 16 + quad * 4;
#pragma unroll
      for (int nt = 0; nt < 4; ++nt) {
        const int gc = n0 + wc * 64 + nt * 16 + l15;
#pragma unroll
        for (int r = 0; r < 4; ++r)
          out[(size_t)(gr + r) * 1024 + gc] = f2b(acc[mt][nt][r]);
      }
    }
  } else {
    // vt[(b*1024 + e)*2048 + s]; 4 consecutive s per lane -> 8B store
#pragma unroll
    for (int mt = 0; mt < 4; ++mt) {
      const int gr = m0 + wr * 64 + mt * 16 + quad * 4;  // token idx b*2048+s
      const int b = gr >> 11;
      const int s = gr & 2047;
#pragma unroll
      for (int nt = 0; nt < 4; ++nt) {
        const int gc = n0 + wc * 64 + nt * 16 + l15;     // embed dim e
        bf16x4 pk = { (short)f2b(acc[mt][nt][0]), (short)f2b(acc[mt][nt][1]),
                      (short)f2b(acc[mt][nt][2]), (short)f2b(acc[mt][nt][3]) };
        *(bf16x4*)&vt[(size_t)(b * 1024 + gc) * 2048 + s] = pk;
      }
    }
  }
}

// ---------------------------------------------------------------------------
// Output projection: out = ctx * Wo^T + bo. ctx bf16 (ws), Wo/bo fp32,
// out fp32 (verified R9).
// ---------------------------------------------------------------------------
__global__ __launch_bounds__(256, 2) void gemm_out_kernel(
    const u16* __restrict__ ctx, const float* __restrict__ wo,
    const float* __restrict__ bo, float* __restrict__ out) {
  __shared__ __align__(16) u16 As[128 * 40];
  __shared__ __align__(16) u16 Bs[128 * 40];
  const int tid = threadIdx.x;
  const int m0 = blockIdx.x * 128;
  const int n0 = blockIdx.y * 128;

  f32x4 acc[4][4] = {};
  gemm_core<false>(ctx, wo, m0, n0, tid, As, Bs, acc);

  const int lane = tid & 63, wave = tid >> 6;
  const int wr = wave >> 1, wc = wave & 1;
  const int l15 = lane & 15, quad = lane >> 4;
#pragma unroll
  for (int nt = 0; nt < 4; ++nt) {
    const int gc = n0 + wc * 64 + nt * 16 + l15;
    const float bv = bo[gc];
#pragma unroll
    for (int mt = 0; mt < 4; ++mt) {
      const int gr = m0 + wr * 64 + mt * 16 + quad * 4;
#pragma unroll
      for (int r = 0; r < 4; ++r)
        out[(size_t)(gr + r) * 1024 + gc] = acc[mt][nt][r] + bv;
    }
  }
}

// ---------------------------------------------------------------------------
// Wave-level MFMA flash v3 = R10's straight-line body (NO dynamically
// indexed register arrays -> no scratch spill; R11 lesson) + two proven
// fixes: P-tile stride 36 (bank-conflict-free; R11 counter-verified) and
// 2-wave blocks with heavy-first LPT mapping q0=(63-bx)*32.
// ctx aliases q: each wave reads only its own (b,rows,h) q-slice at start,
// writes the identical slice at the end; all slices disjoint across waves.
// ---------------------------------------------------------------------------
__global__ __launch_bounds__(128, 4) void flash_kernel(
    const u16* q, const u16* __restrict__ k,
    const u16* __restrict__ vt, u16* ctx) {
  __shared__ __align__(16) u16 plds_all[2][16 * 36];
  const int tid = threadIdx.x;
  const int wave = tid >> 6, lane = tid & 63;
  const int l15 = lane & 15, quad = lane >> 4;
  const int q0 = (63 - (int)blockIdx.x) * 32 + wave * 16;  // heavy-first LPT
  const int bh = blockIdx.y;
  const int b = bh >> 4, h = bh & 15;
  const int m = q0 + l15;  // q-row this lane owns (as C-layout column)

  const u16* qrow = q + ((size_t)(b * 2048 + m) * 1024 + h * 64);
  const bf16x8 qf0 = *(const bf16x8*)(qrow + quad * 8);
  const bf16x8 qf1 = *(const bf16x8*)(qrow + 32 + quad * 8);
  const u16* kbase = k + (size_t)(b * 2048) * 1024 + h * 64;
  const u16* vbase = vt + (size_t)(b * 1024 + h * 64) * 2048;
  u16* plds = plds_all[wave];

  f32x4 o[4] = {};
  float m_run = -INFINITY, l_run = 0.0f;

  const int ntiles = (q0 + 47) >> 5;  // kv tiles of 32 covering kv <= q0+15
  for (int t = 0; t < ntiles; ++t) {
    const int n0 = t * 32;
    const u16* kr0 = kbase + (size_t)(n0 + l15) * 1024 + quad * 8;
    const u16* kr1 = kbase + (size_t)(n0 + 16 + l15) * 1024 + quad * 8;
    const bf16x8 kf00 = *(const bf16x8*)(kr0);
    const bf16x8 kf01 = *(const bf16x8*)(kr0 + 32);
    const bf16x8 kf10 = *(const bf16x8*)(kr1);
    const bf16x8 kf11 = *(const bf16x8*)(kr1 + 32);
    // V loads are dependence-free; issue alongside K.
    const bf16x8 vf0 = *(const bf16x8*)(vbase + (size_t)(0 * 16 + l15) * 2048 + n0 + quad * 8);
    const bf16x8 vf1 = *(const bf16x8*)(vbase + (size_t)(1 * 16 + l15) * 2048 + n0 + quad * 8);
    const bf16x8 vf2 = *(const bf16x8*)(vbase + (size_t)(2 * 16 + l15) * 2048 + n0 + quad * 8);
    const bf16x8 vf3 = *(const bf16x8*)(vbase + (size_t)(3 * 16 + l15) * 2048 + n0 + quad * 8);

    f32x4 st0 = {}, st1 = {};
    st0 = __builtin_amdgcn_mfma_f32_16x16x32_bf16(kf00, qf0, st0, 0, 0, 0);
    st0 = __builtin_amdgcn_mfma_f32_16x16x32_bf16(kf01, qf1, st0, 0, 0, 0);
    st1 = __builtin_amdgcn_mfma_f32_16x16x32_bf16(kf10, qf0, st1, 0, 0, 0);
    st1 = __builtin_amdgcn_mfma_f32_16x16x32_bf16(kf11, qf1, st1, 0, 0, 0);

    float s[8];
#pragma unroll
    for (int r = 0; r < 4; ++r) {
      s[r] = st0[r] * 0.125f;
      s[4 + r] = st1[r] * 0.125f;
    }
    const int nb = n0 + quad * 4;  // st0 reg r -> kv=nb+r; st1 -> kv=nb+16+r
#pragma unroll
    for (int r = 0; r < 4; ++r) {
      if (nb + r > m) s[r] = -INFINITY;
      if (nb + 16 + r > m) s[4 + r] = -INFINITY;
    }
    float mx = s[0];
#pragma unroll
    for (int i = 1; i < 8; ++i) mx = fmaxf(mx, s[i]);
    mx = fmaxf(mx, __shfl_xor(mx, 16));
    mx = fmaxf(mx, __shfl_xor(mx, 32));
    const float m_new = fmaxf(m_run, mx);
    const float alpha = exp2f((m_run - m_new) * LOG2E);  // 0 on first tile

    float p[8];
    float sum = 0.0f;
#pragma unroll
    for (int i = 0; i < 8; ++i) {
      p[i] = exp2f((s[i] - m_new) * LOG2E);
      sum += p[i];
    }
    sum += __shfl_xor(sum, 16);
    sum += __shfl_xor(sum, 32);
    l_run = l_run * alpha + sum;
    m_run = m_new;
#pragma unroll
    for (int dt = 0; dt < 4; ++dt) o[dt] *= alpha;

    // P (C-layout) -> LDS [q][kv'] (stride 36, conflict-free) -> A-layout
    bf16x4 pk0 = { (short)f2b(p[0]), (short)f2b(p[1]),
                   (short)f2b(p[2]), (short)f2b(p[3]) };
    bf16x4 pk1 = { (short)f2b(p[4]), (short)f2b(p[5]),
                   (short)f2b(p[6]), (short)f2b(p[7]) };
    *(bf16x4*)&plds[l15 * 36 + quad * 4] = pk0;
    *(bf16x4*)&plds[l15 * 36 + 16 + quad * 4] = pk1;
    asm volatile("s_waitcnt lgkmcnt(0)" ::: "memory");
    const bf16x8 pf = *(const bf16x8*)&plds[l15 * 36 + quad * 8];

    o[0] = __builtin_amdgcn_mfma_f32_16x16x32_bf16(vf0, pf, o[0], 0, 0, 0);
    o[1] = __builtin_amdgcn_mfma_f32_16x16x32_bf16(vf1, pf, o[1], 0, 0, 0);
    o[2] = __builtin_amdgcn_mfma_f32_16x16x32_bf16(vf2, pf, o[2], 0, 0, 0);
    o[3] = __builtin_amdgcn_mfma_f32_16x16x32_bf16(vf3, pf, o[3], 0, 0, 0);
  }

  const float inv = 1.0f / l_run;
  u16* crow = ctx + ((size_t)(b * 2048 + q0 + l15) * 1024 + h * 64);
#pragma unroll
  for (int dt = 0; dt < 4; ++dt) {
    bf16x4 ov = { (short)f2b(o[dt][0] * inv), (short)f2b(o[dt][1] * inv),
                  (short)f2b(o[dt][2] * inv), (short)f2b(o[dt][3] * inv) };
    *(bf16x4*)&crow[dt * 16 + quad * 4] = ov;
  }
}

// ---------------------------------------------------------------------------
extern "C" void kernel_launch(void* const* d_in, const int* in_sizes, int n_in,
                              void* d_out, int out_size, void* d_ws,
                              size_t ws_size, hipStream_t stream) {
  // Interface (R9-verified): inputs fp32 in dict order, output fp32.
  const float* x  = (const float*)d_in[0];
  const float* wq = (const float*)d_in[1];
  const float* wk = (const float*)d_in[2];
  const float* wv = (const float*)d_in[3];
  const float* wo = (const float*)d_in[4];
  const float* bo = (const float*)d_in[5];
  float* out = (float*)d_out;

  // ws (bf16 elems): qb [0,4M) (aliased as ctx), kb [4M,8M),
  // vt [8M,12M) transposed V. 24 MiB.
  u16* qb = (u16*)d_ws;
  u16* kb = qb + 4194304u;
  u16* vt = kb + 4194304u;
  u16* ctx = qb;

  gemm_qkv_kernel<<<dim3(32, 24), 256, 0, stream>>>(x, wq, wk, wv, qb, kb, vt);
  flash_kernel<<<dim3(64, 32), 128, 0, stream>>>(qb, kb, vt, ctx);
  gemm_out_kernel<<<dim3(32, 8), 256, 0, stream>>>(ctx, wo, bo, out);
}